// Round 11
// 393.386 us; speedup vs baseline: 1.0704x; 1.0704x over previous
//
#include <hip/hip_runtime.h>
#include <math.h>

#define B_ 32
#define H_ 112
#define W_ 112
#define C_ 128
#define R_ 2048
#define HW_ (H_ * W_)      // 12544
#define C4_ (C_ / 4)       // 32 float4 per pixel
#define PB_ 32             // pool blocks per batch
#define RB_ 8              // r-blocks per batch in fc (256 r each)

typedef float f32x4_t __attribute__((ext_vector_type(4)));

// ---------------------------------------------------------------------------
// Kernel 1: pool partials. grid (B, PB_). Each block reduces 392 pixels and
// writes one 128-float partial vector (no atomics, no memset needed).
// Wave reads 1 KB contiguous (2 pixels of 128ch fp32).
// ---------------------------------------------------------------------------
__global__ __launch_bounds__(256) void pool_kernel(const float4* __restrict__ x,
                                                   float4* __restrict__ part) {
    const int b     = blockIdx.x;       // 0..31
    const int pb    = blockIdx.y;       // 0..PB_-1
    const int t     = threadIdx.x;      // 0..255
    const int lane4 = t & 31;           // float4 slot (channel/4)
    const int prow  = t >> 5;           // 0..7

    const int pixels_per_block = HW_ / PB_;  // 392
    const int p0 = pb * pixels_per_block;
    const float4* xb = x + (size_t)b * HW_ * C4_;

    float4 acc = make_float4(0.f, 0.f, 0.f, 0.f);
    for (int p = p0 + prow; p < p0 + pixels_per_block; p += 8) {
        float4 v = xb[(size_t)p * C4_ + lane4];
        acc.x += v.x; acc.y += v.y; acc.z += v.z; acc.w += v.w;
    }

    __shared__ float4 red[256];
    red[t] = acc;
    __syncthreads();
    if (t < 32) {
        float4 a = red[t];
#pragma unroll
        for (int k = 1; k < 8; ++k) {
            float4 v = red[t + 32 * k];
            a.x += v.x; a.y += v.y; a.z += v.z; a.w += v.w;
        }
        part[((size_t)b * PB_ + pb) * C4_ + t] = a;
    }
}

// ---------------------------------------------------------------------------
// Kernel 2 (fused fc1+fc2-partial): grid = B*RB_ blocks of 256.
// Each block: reduce part -> mean (redundant per batch, ~16 KB L2 reads),
// compute its 256-row slice of h = gelu_tanh(s.w1 + b1) ENTIRELY IN LDS,
// then immediately contract that slice against w2 rows [rb*256, rb*256+256)
// to produce a partial g contribution gpart[b][rb][c]. This removes the h
// global round-trip AND fc2's old 32-block (1 block/CU) serialization:
// w2 reads are now spread across 256 blocks just like w1.
// ---------------------------------------------------------------------------
__global__ __launch_bounds__(256) void fc_kernel(const float4* __restrict__ part,
                                                 const float* __restrict__ w1,
                                                 const float* __restrict__ b1,
                                                 const float4* __restrict__ w2,
                                                 float4* __restrict__ gpart) {
    const int b  = blockIdx.x >> 3;
    const int rb = blockIdx.x & 7;
    const int t  = threadIdx.x;
    const int r  = rb * 256 + t;

    __shared__ float  sl[C_];
    __shared__ float  hl[256];
    __shared__ float4 red[256];

    if (t < 32) {
        float4 a = make_float4(0.f, 0.f, 0.f, 0.f);
#pragma unroll 8
        for (int k = 0; k < PB_; ++k) {
            float4 v = part[((size_t)b * PB_ + k) * C4_ + t];
            a.x += v.x; a.y += v.y; a.z += v.z; a.w += v.w;
        }
        const float inv = 1.0f / (float)HW_;
        sl[t * 4 + 0] = a.x * inv;
        sl[t * 4 + 1] = a.y * inv;
        sl[t * 4 + 2] = a.z * inv;
        sl[t * 4 + 3] = a.w * inv;
    }
    __syncthreads();

    // --- fc1 slice: h[r] for r = rb*256 + t (w1 column reads coalesced) ---
    float acc = b1[r];
#pragma unroll 8
    for (int c = 0; c < C_; ++c)
        acc += sl[c] * w1[(size_t)c * R_ + r];

    // tanh-approx GELU: 0.5x(1+tanh(sqrt(2/pi)(x+0.044715x^3)))
    const float xv = acc;
    const float tn = tanhf(0.7978845608028654f * (xv + 0.044715f * xv * xv * xv));
    hl[t] = 0.5f * xv * (1.0f + tn);
    __syncthreads();

    // --- fc2 partial: contract this 256-row h slice against w2 ---
    const int c4 = t & 31;   // float4 column group
    const int ks = t >> 5;   // 0..7 K-sub-slice (32 rows each)
    float4 a2 = make_float4(0.f, 0.f, 0.f, 0.f);
    const int rr0 = ks * 32;
#pragma unroll 8
    for (int rr = rr0; rr < rr0 + 32; ++rr) {
        const float hv = hl[rr];
        float4 w = w2[(size_t)(rb * 256 + rr) * C4_ + c4];
        a2.x += hv * w.x; a2.y += hv * w.y; a2.z += hv * w.z; a2.w += hv * w.w;
    }
    red[t] = a2;
    __syncthreads();
    if (t < 32) {
        float4 a = red[t];
#pragma unroll
        for (int k = 1; k < 8; ++k) {
            float4 v = red[t + 32 * k];
            a.x += v.x; a.y += v.y; a.z += v.z; a.w += v.w;
        }
        gpart[((size_t)b * RB_ + rb) * C4_ + t] = a;
    }
}

// ---------------------------------------------------------------------------
// Kernel 3: out = x * sigmoid(sum_rb gpart + b2). Gate finalize is computed
// redundantly per block (8 independent 16B L2-hit loads + 4 expf — trivial
// vs the 200 KB this block streams). float4 grid-stride; stride % 32 == 0 so
// the gate is loop-invariant per thread. NON-TEMPORAL stores for out: out is
// never re-read, and keeping it out of L2/L3 preserves x's L3 residency
// (x = 196 MiB fits the 256 MiB Infinity Cache) so this pass's x-read hits
// L3, not HBM.
// ---------------------------------------------------------------------------
__global__ __launch_bounds__(256) void scale_kernel(const float4* __restrict__ x,
                                                    const float4* __restrict__ gpart,
                                                    const float* __restrict__ b2,
                                                    float4* __restrict__ out) {
    const int b  = blockIdx.x;
    const int t  = threadIdx.x;
    const int c4 = t & 31;

    // finalize gate for this thread's channel group
    const float4* gp = gpart + (size_t)b * RB_ * C4_;
    float4 a = gp[c4];
#pragma unroll
    for (int k = 1; k < RB_; ++k) {
        float4 v = gp[(size_t)k * C4_ + c4];
        a.x += v.x; a.y += v.y; a.z += v.z; a.w += v.w;
    }
    a.x += b2[c4 * 4 + 0]; a.y += b2[c4 * 4 + 1];
    a.z += b2[c4 * 4 + 2]; a.w += b2[c4 * 4 + 3];
    float4 gv;
    gv.x = 1.0f / (1.0f + expf(-a.x));
    gv.y = 1.0f / (1.0f + expf(-a.y));
    gv.z = 1.0f / (1.0f + expf(-a.z));
    gv.w = 1.0f / (1.0f + expf(-a.w));

    const size_t base = (size_t)b * HW_ * C4_;
    const int total = HW_ * C4_;  // 401408 float4 per batch
    const int stride = gridDim.y * 256;

    for (int i = blockIdx.y * 256 + t; i < total; i += stride) {
        float4 v = x[base + i];
        f32x4_t o;
        o.x = v.x * gv.x; o.y = v.y * gv.y; o.z = v.z * gv.z; o.w = v.w * gv.w;
        __builtin_nontemporal_store(o, (f32x4_t*)&out[base + i]);
    }
}

extern "C" void kernel_launch(void* const* d_in, const int* in_sizes, int n_in,
                              void* d_out, int out_size, void* d_ws, size_t ws_size,
                              hipStream_t stream) {
    const float* x  = (const float*)d_in[0];
    const float* w1 = (const float*)d_in[1];
    const float* b1 = (const float*)d_in[2];
    const float* w2 = (const float*)d_in[3];
    const float* b2 = (const float*)d_in[4];
    float* out = (float*)d_out;

    // workspace: part[B*PB_*C] (512 KB) | gpart[B*RB_*C] (128 KB)
    float* part  = (float*)d_ws;
    float* gpart = part + B_ * PB_ * C_;

    pool_kernel<<<dim3(B_, PB_), 256, 0, stream>>>((const float4*)x, (float4*)part);
    fc_kernel<<<B_ * RB_, 256, 0, stream>>>((const float4*)part, w1, b1,
                                            (const float4*)w2, (float4*)gpart);
    scale_kernel<<<dim3(B_, 64), 256, 0, stream>>>((const float4*)x,
                                                   (const float4*)gpart, b2,
                                                   (float4*)out);
}

// Round 18
// 392.695 us; speedup vs baseline: 1.0723x; 1.0018x over previous
//
#include <hip/hip_runtime.h>
#include <hip/hip_cooperative_groups.h>
#include <math.h>

namespace cg = cooperative_groups;

#define B_ 32
#define H_ 112
#define W_ 112
#define C_ 128
#define R_ 2048
#define HW_ (H_ * W_)      // 12544
#define C4_ (C_ / 4)       // 32 float4 per pixel
#define PB_ 32             // pool chunks per batch
#define RB_ 8              // r-blocks per batch in fc (256 r each)
#define NB_ (B_ * PB_)     // 1024 blocks, 4/CU on 256 CUs -> co-resident

typedef float f32x4_t __attribute__((ext_vector_type(4)));

// ---------------------------------------------------------------------------
// Fused cooperative kernel: pool -> grid.sync -> fc1+fc2 -> grid.sync -> scale
// Phase bodies are verbatim ports of the proven 3-kernel pipeline (393 us).
// ONLY launched when the stream is NOT capturing (coop launch inside graph
// capture can abort the process rather than return an error).
// ---------------------------------------------------------------------------
__global__ __launch_bounds__(256, 4) void fused_kernel(
    const float4* __restrict__ x, const float* __restrict__ w1,
    const float* __restrict__ b1, const float4* __restrict__ w2,
    const float* __restrict__ b2, float4* __restrict__ part,
    float4* __restrict__ gpart, float4* __restrict__ out)
{
    cg::grid_group grid = cg::this_grid();
    const int blk = blockIdx.x;
    const int t   = threadIdx.x;

    __shared__ float4 red[256];
    __shared__ float  sl[C_];
    __shared__ float  hl[256];

    // ---- phase 1: pool partials ----
    {
        const int b     = blk >> 5;          // 0..31
        const int pb    = blk & 31;          // 0..31
        const int lane4 = t & 31;
        const int prow  = t >> 5;
        const int ppb   = HW_ / PB_;         // 392
        const int p0    = pb * ppb;
        const float4* xb = x + (size_t)b * HW_ * C4_;

        float4 acc = make_float4(0.f, 0.f, 0.f, 0.f);
        for (int p = p0 + prow; p < p0 + ppb; p += 8) {
            float4 v = xb[(size_t)p * C4_ + lane4];
            acc.x += v.x; acc.y += v.y; acc.z += v.z; acc.w += v.w;
        }
        red[t] = acc;
        __syncthreads();
        if (t < 32) {
            float4 a = red[t];
#pragma unroll
            for (int k = 1; k < 8; ++k) {
                float4 v = red[t + 32 * k];
                a.x += v.x; a.y += v.y; a.z += v.z; a.w += v.w;
            }
            part[((size_t)b * PB_ + pb) * C4_ + t] = a;
        }
    }
    grid.sync();

    // ---- phase 2: fc1+fc2 partial, blocks 0..255 ----
    if (blk < B_ * RB_) {
        const int b  = blk >> 3;
        const int rb = blk & 7;
        const int r  = rb * 256 + t;

        if (t < 32) {
            float4 a = make_float4(0.f, 0.f, 0.f, 0.f);
#pragma unroll 8
            for (int k = 0; k < PB_; ++k) {
                float4 v = part[((size_t)b * PB_ + k) * C4_ + t];
                a.x += v.x; a.y += v.y; a.z += v.z; a.w += v.w;
            }
            const float inv = 1.0f / (float)HW_;
            sl[t * 4 + 0] = a.x * inv;
            sl[t * 4 + 1] = a.y * inv;
            sl[t * 4 + 2] = a.z * inv;
            sl[t * 4 + 3] = a.w * inv;
        }
        __syncthreads();

        float acc = b1[r];
#pragma unroll 8
        for (int c = 0; c < C_; ++c)
            acc += sl[c] * w1[(size_t)c * R_ + r];

        // tanh-approx GELU
        const float xv = acc;
        const float tn = tanhf(0.7978845608028654f * (xv + 0.044715f * xv * xv * xv));
        hl[t] = 0.5f * xv * (1.0f + tn);
        __syncthreads();

        const int c4 = t & 31;
        const int ks = t >> 5;
        float4 a2 = make_float4(0.f, 0.f, 0.f, 0.f);
        const int rr0 = ks * 32;
#pragma unroll 8
        for (int rr = rr0; rr < rr0 + 32; ++rr) {
            const float hv = hl[rr];
            float4 w = w2[(size_t)(rb * 256 + rr) * C4_ + c4];
            a2.x += hv * w.x; a2.y += hv * w.y; a2.z += hv * w.z; a2.w += hv * w.w;
        }
        red[t] = a2;
        __syncthreads();
        if (t < 32) {
            float4 a = red[t];
#pragma unroll
            for (int k = 1; k < 8; ++k) {
                float4 v = red[t + 32 * k];
                a.x += v.x; a.y += v.y; a.z += v.z; a.w += v.w;
            }
            gpart[((size_t)b * RB_ + rb) * C4_ + t] = a;
        }
    }
    grid.sync();

    // ---- phase 3: scale; each block streams the chunk it pooled ----
    {
        const int b  = blk >> 5;
        const int pb = blk & 31;
        const int c4 = t & 31;

        const float4* gp = gpart + (size_t)b * RB_ * C4_;
        float4 a = gp[c4];
#pragma unroll
        for (int k = 1; k < RB_; ++k) {
            float4 v = gp[(size_t)k * C4_ + c4];
            a.x += v.x; a.y += v.y; a.z += v.z; a.w += v.w;
        }
        a.x += b2[c4 * 4 + 0]; a.y += b2[c4 * 4 + 1];
        a.z += b2[c4 * 4 + 2]; a.w += b2[c4 * 4 + 3];
        float4 gv;
        gv.x = 1.0f / (1.0f + expf(-a.x));
        gv.y = 1.0f / (1.0f + expf(-a.y));
        gv.z = 1.0f / (1.0f + expf(-a.z));
        gv.w = 1.0f / (1.0f + expf(-a.w));

        const int ppb = HW_ / PB_;                       // 392 pixels
        const size_t base = (size_t)b * HW_ * C4_ + (size_t)pb * ppb * C4_;
        const int n = ppb * C4_;                         // 12544 float4
        for (int i = t; i < n; i += 256) {               // i%32 == t%32 -> gate invariant
            float4 v = x[base + i];
            f32x4_t o;
            o.x = v.x * gv.x; o.y = v.y * gv.y; o.z = v.z * gv.z; o.w = v.w * gv.w;
            __builtin_nontemporal_store(o, (f32x4_t*)&out[base + i]);
        }
    }
}

// ---------------------------------------------------------------------------
// Proven 3-kernel pipeline (393.4 us, verified round 11). Used whenever the
// stream is capturing (graph-safe path) or the coop launch is rejected.
// ---------------------------------------------------------------------------
__global__ __launch_bounds__(256) void pool_kernel(const float4* __restrict__ x,
                                                   float4* __restrict__ part) {
    const int b     = blockIdx.x;
    const int pb    = blockIdx.y;
    const int t     = threadIdx.x;
    const int lane4 = t & 31;
    const int prow  = t >> 5;

    const int pixels_per_block = HW_ / PB_;
    const int p0 = pb * pixels_per_block;
    const float4* xb = x + (size_t)b * HW_ * C4_;

    float4 acc = make_float4(0.f, 0.f, 0.f, 0.f);
    for (int p = p0 + prow; p < p0 + pixels_per_block; p += 8) {
        float4 v = xb[(size_t)p * C4_ + lane4];
        acc.x += v.x; acc.y += v.y; acc.z += v.z; acc.w += v.w;
    }

    __shared__ float4 red[256];
    red[t] = acc;
    __syncthreads();
    if (t < 32) {
        float4 a = red[t];
#pragma unroll
        for (int k = 1; k < 8; ++k) {
            float4 v = red[t + 32 * k];
            a.x += v.x; a.y += v.y; a.z += v.z; a.w += v.w;
        }
        part[((size_t)b * PB_ + pb) * C4_ + t] = a;
    }
}

__global__ __launch_bounds__(256) void fc_kernel(const float4* __restrict__ part,
                                                 const float* __restrict__ w1,
                                                 const float* __restrict__ b1,
                                                 const float4* __restrict__ w2,
                                                 float4* __restrict__ gpart) {
    const int b  = blockIdx.x >> 3;
    const int rb = blockIdx.x & 7;
    const int t  = threadIdx.x;
    const int r  = rb * 256 + t;

    __shared__ float  sl[C_];
    __shared__ float  hl[256];
    __shared__ float4 red[256];

    if (t < 32) {
        float4 a = make_float4(0.f, 0.f, 0.f, 0.f);
#pragma unroll 8
        for (int k = 0; k < PB_; ++k) {
            float4 v = part[((size_t)b * PB_ + k) * C4_ + t];
            a.x += v.x; a.y += v.y; a.z += v.z; a.w += v.w;
        }
        const float inv = 1.0f / (float)HW_;
        sl[t * 4 + 0] = a.x * inv;
        sl[t * 4 + 1] = a.y * inv;
        sl[t * 4 + 2] = a.z * inv;
        sl[t * 4 + 3] = a.w * inv;
    }
    __syncthreads();

    float acc = b1[r];
#pragma unroll 8
    for (int c = 0; c < C_; ++c)
        acc += sl[c] * w1[(size_t)c * R_ + r];

    const float xv = acc;
    const float tn = tanhf(0.7978845608028654f * (xv + 0.044715f * xv * xv * xv));
    hl[t] = 0.5f * xv * (1.0f + tn);
    __syncthreads();

    const int c4 = t & 31;
    const int ks = t >> 5;
    float4 a2 = make_float4(0.f, 0.f, 0.f, 0.f);
    const int rr0 = ks * 32;
#pragma unroll 8
    for (int rr = rr0; rr < rr0 + 32; ++rr) {
        const float hv = hl[rr];
        float4 w = w2[(size_t)(rb * 256 + rr) * C4_ + c4];
        a2.x += hv * w.x; a2.y += hv * w.y; a2.z += hv * w.z; a2.w += hv * w.w;
    }
    red[t] = a2;
    __syncthreads();
    if (t < 32) {
        float4 a = red[t];
#pragma unroll
        for (int k = 1; k < 8; ++k) {
            float4 v = red[t + 32 * k];
            a.x += v.x; a.y += v.y; a.z += v.z; a.w += v.w;
        }
        gpart[((size_t)b * RB_ + rb) * C4_ + t] = a;
    }
}

__global__ __launch_bounds__(256) void scale_kernel(const float4* __restrict__ x,
                                                    const float4* __restrict__ gpart,
                                                    const float* __restrict__ b2,
                                                    float4* __restrict__ out) {
    const int b  = blockIdx.x;
    const int t  = threadIdx.x;
    const int c4 = t & 31;

    const float4* gp = gpart + (size_t)b * RB_ * C4_;
    float4 a = gp[c4];
#pragma unroll
    for (int k = 1; k < RB_; ++k) {
        float4 v = gp[(size_t)k * C4_ + c4];
        a.x += v.x; a.y += v.y; a.z += v.z; a.w += v.w;
    }
    a.x += b2[c4 * 4 + 0]; a.y += b2[c4 * 4 + 1];
    a.z += b2[c4 * 4 + 2]; a.w += b2[c4 * 4 + 3];
    float4 gv;
    gv.x = 1.0f / (1.0f + expf(-a.x));
    gv.y = 1.0f / (1.0f + expf(-a.y));
    gv.z = 1.0f / (1.0f + expf(-a.z));
    gv.w = 1.0f / (1.0f + expf(-a.w));

    const size_t base = (size_t)b * HW_ * C4_;
    const int total = HW_ * C4_;
    const int stride = gridDim.y * 256;

    for (int i = blockIdx.y * 256 + t; i < total; i += stride) {
        float4 v = x[base + i];
        f32x4_t o;
        o.x = v.x * gv.x; o.y = v.y * gv.y; o.z = v.z * gv.z; o.w = v.w * gv.w;
        __builtin_nontemporal_store(o, (f32x4_t*)&out[base + i]);
    }
}

extern "C" void kernel_launch(void* const* d_in, const int* in_sizes, int n_in,
                              void* d_out, int out_size, void* d_ws, size_t ws_size,
                              hipStream_t stream) {
    const float4* x  = (const float4*)d_in[0];
    const float*  w1 = (const float*)d_in[1];
    const float*  b1 = (const float*)d_in[2];
    const float4* w2 = (const float4*)d_in[3];
    const float*  b2 = (const float*)d_in[4];
    float4* out = (float4*)d_out;

    // workspace: part[B*PB_*C] (512 KB) | gpart[B*RB_*C] (128 KB)
    float4* part  = (float4*)d_ws;
    float4* gpart = (float4*)((float*)d_ws + B_ * PB_ * C_);

    // Cooperative launch inside a capturing stream can abort the process
    // (graph-capture tripwire) instead of returning an error. Query capture
    // state first (read-only host API, capture-safe) and only attempt the
    // coop path on a non-capturing stream.
    hipStreamCaptureStatus cap = hipStreamCaptureStatusNone;
    unsigned long long cap_id = 0;
    (void)hipStreamGetCaptureInfo(stream, &cap, &cap_id);

    if (cap == hipStreamCaptureStatusNone) {
        void* args[] = {(void*)&x, (void*)&w1, (void*)&b1, (void*)&w2,
                        (void*)&b2, (void*)&part, (void*)&gpart, (void*)&out};
        hipError_t err = hipLaunchCooperativeKernel((void*)fused_kernel,
                                                    dim3(NB_), dim3(256),
                                                    args, 0, stream);
        if (err == hipSuccess) return;
        (void)hipGetLastError();  // clear sticky error before fallback
    }

    // Graph-safe proven pipeline (393.4 us verified).
    pool_kernel<<<dim3(B_, PB_), 256, 0, stream>>>(x, part);
    fc_kernel<<<B_ * RB_, 256, 0, stream>>>(part, w1, b1, w2, gpart);
    scale_kernel<<<dim3(B_, 64), 256, 0, stream>>>(x, gpart, (const float*)b2, out);
}